// Round 13
// baseline (305.345 us; speedup 1.0000x reference)
//
#include <hip/hip_runtime.h>

// NODEModel MFMA fp16, R13 = R12 + uniform DMA staging (vmcnt ledger fix).
// R12 residual bug: at c==3, sw>=11 the next-slab stage was skipped, so the
// steady-state "2 DMAs in flight" invariant broke and vmcnt(1) at c=3,sw=12
// passed WITHOUT waiting for slab 12's DMA -> sporadically stale final-layer
// weights. Fix: always stage; at the last-chain tail, prefetch dp slabs 0/1
// into the (dead) ring slot -- harmless, keeps the ledger uniform.
// Structure (R11/R12): wave = 32 samples x 64 feats (acc 32 AGPR), block 512
// = 4 sample-groups x 2 feat-halves, launch_bounds(512,4) -> <=96 VGPR + 32
// AGPR, LDS 64KB (H 32K + 4-slot ring 32K) -> 2 blocks/CU = 4 waves/SIMD.
// Sync: per-slab s_waitcnt vmcnt(1),lgkm(0) + raw s_barrier; ks==3 mid-slab
// lgkm(0)+barrier (cross-wave RAW fix); vm(0) barrier before output layer.

#define NTHREADS 512
#define MLP_STRIDE 53248   // fp16 elems per MLP: 4096 WinA + 3*16384 Wh = 13 slabs
#define WINA_ELEMS 4096
#define SLAB_F16 4096      // 8 KB slab
#define TANH_SCALE 2.8853900817779268f   // 2*log2(e)

#define LDS_W 32768        // ring base; slots at +0,+8192,+16384,+24576

typedef _Float16 f16;
typedef f16 f16x8 __attribute__((ext_vector_type(8)));
typedef __fp16 fp16x2 __attribute__((ext_vector_type(2)));
typedef float f32x4 __attribute__((ext_vector_type(4)));

// ---------------- prep: fp32 weights -> fp16 fragment-linear (pre-scaled) ----
__global__ __launch_bounds__(256)
void prep_kernel(const float* __restrict__ dp_Win, const float* __restrict__ dp_bin,
                 const float* __restrict__ dp_Wh,  const float* __restrict__ dp_bh,
                 const float* __restrict__ ic_Win, const float* __restrict__ ic_bin,
                 const float* __restrict__ ic_Wh,  const float* __restrict__ ic_bh,
                 f16* __restrict__ wsw)
{
    int e = blockIdx.x * 256 + threadIdx.x;
    if (e >= 2 * MLP_STRIDE + 768) return;
    if (e >= 2 * MLP_STRIDE) {          // scaled hidden biases, fp32
        int idx = e - 2 * MLP_STRIDE;   // [mlp(2)][l(3)][m(128)]
        int mlp = idx / 384, rem = idx % 384;
        const float* bh = mlp ? ic_bh : dp_bh;
        float* bsc = (float*)(wsw + 2 * MLP_STRIDE);
        bsc[idx] = bh[rem] * TANH_SCALE;
        return;
    }
    int mlp = (e >= MLP_STRIDE) ? 1 : 0;   // 0 = dp, 1 = ic
    int r = e - mlp * MLP_STRIDE;
    const float* Win = mlp ? ic_Win : dp_Win;
    const float* bin = mlp ? ic_bin : dp_bin;
    const float* Wh  = mlp ? ic_Wh  : dp_Wh;
    float val;
    if (r < WINA_ELEMS) {
        int mt = r >> 9, lane = (r >> 3) & 63, j = r & 7;
        int m = mt * 16 + (lane & 15);
        int k = ((lane >> 4) << 3) + j;                     // 0..31
        if (mlp) {  // ic remapped to dp-style layout: k=0 zero, 1..5 feats, 6 bias
            val = (k >= 1 && k <= 5) ? Win[(k - 1) * 128 + m]
                : ((k == 6) ? bin[m] : 0.0f);
        } else {    // dp: feats k=0..5, bias k=6
            val = (k < 6) ? Win[k * 128 + m] : ((k == 6) ? bin[m] : 0.0f);
        }
    } else {
        int r2 = r - WINA_ELEMS;
        int l = r2 >> 14, r3 = r2 & 16383;
        int ks = r3 >> 12, mt = (r3 >> 9) & 7, lane = (r3 >> 3) & 63, j = r3 & 7;
        int m = mt * 16 + (lane & 15);
        int k = ks * 32 + ((lane >> 4) << 3) + j;           // 0..127
        val = Wh[(l * 128 + k) * 128 + m];
    }
    wsw[e] = (f16)(val * TANH_SCALE);
}

// ---------------- main ----------------
__device__ __forceinline__ float tanh_fast(float x) {
    // input pre-scaled by 2*log2e: tanh = 1 - 2/(exp2(x)+1)
    float e = __builtin_amdgcn_exp2f(x);
    float r = __builtin_amdgcn_rcpf(e + 1.0f);
    return fmaf(-2.0f, r, 1.0f);
}

__device__ __forceinline__ unsigned int pk16(float a, float b) {
    union { fp16x2 h; unsigned int u; } c;
    c.h = __builtin_amdgcn_cvt_pkrtz(a, b);
    return c.u;
}

__device__ __forceinline__ int h_addr(int n, int kb) {
    return n * 256 + ((((kb >> 4) ^ (n & 7)) << 4) | (kb & 15));
}

__device__ __forceinline__ f32x4 mfma16(f16x8 a, f16x8 b, f32x4 c) {
    return __builtin_amdgcn_mfma_f32_16x16x32_f16(a, b, c, 0, 0, 0);
}

__device__ __forceinline__ void stage16(const void* g, void* l) {
    __builtin_amdgcn_global_load_lds((const __attribute__((address_space(1))) void*)g,
                                     (__attribute__((address_space(3))) void*)l, 16, 0, 0);
}

// s_waitcnt imm (gfx9): vm[3:0] | exp[2:0]<<4 | lgkm[3:0]<<8 | vm[5:4]<<14
#define WAITCNT_VM1_LGKM0 0x0071   // vmcnt=1, lgkmcnt=0
#define WAITCNT_VM0_LGKM0 0x0070   // vmcnt=0, lgkmcnt=0
#define WAITCNT_LGKM0     0xC07F   // vmcnt=63 (no wait), lgkmcnt=0

__global__ __launch_bounds__(NTHREADS, 4)
void node_main(const float* __restrict__ tx, const f16* __restrict__ wsw,
               const float* __restrict__ dp_Wout, const float* __restrict__ dp_bout,
               const float* __restrict__ ic_Wout, const float* __restrict__ ic_bout,
               float* __restrict__ out)
{
    __shared__ __align__(16) unsigned char lds[65536];   // [0,32K) H, [32K,64K) ring

    const int tid  = threadIdx.x;
    const int lane = tid & 63;
    const int wv   = tid >> 6;        // 0..7
    const int g    = wv >> 1;         // sample group 0..3
    const int fh   = wv & 1;          // feature half
    const int q    = lane >> 4;
    const int l15  = lane & 15;
    const int p0   = blockIdx.x * 128;
    const int n0   = g * 32 + l15;
    const int d    = l15 & 7;

    // compact swizzle state (R10-verified decomposition)
    const int basen = n0 * 256;
    const int K    = basen + ((q & 1) << 3) + ((((q >> 1) ^ d) & 1) << 4);
    const int dh32 = (d >> 1) << 5;
    const int Kr   = basen + ((q ^ (d & 3)) << 4);
    const int dk64 = (d >> 2) << 6;
    const int lane16 = (lane << 4) + fh * 4096;   // A-frag: wave's mt-half offset
    const int mtb  = fh * 4;                      // global mt = mtb + mtl

    const float* bsc = (const float*)(wsw + 2 * MLP_STRIDE);

    const float4* tx4 = (const float4*)tx;
    float4 t0v = tx4[p0 + n0];
    float4 t1v = tx4[p0 + n0 + 16];
    float4 tov = tx4[p0 + (tid >> 2)];

    // B templates: [0, r, x, y, z, i, 1, 0] (slot0 patched per dp chain)
    f16x8 bt0 = {}, bt1 = {};
    float a0, a1, ao, io;
    {
        float xx = t0v.y, yy = t0v.z, zz = t0v.w;
        float rr = sqrtf(fmaf(xx, xx, fmaf(yy, yy, zz * zz)));
        float irs = 1.0f / fmaxf(rr, 1e-8f);
        if (lane < 16) {
            bt0[1] = (f16)rr; bt0[2] = (f16)(xx * irs); bt0[3] = (f16)(yy * irs);
            bt0[4] = (f16)(zz * irs); bt0[5] = (f16)(1.0f / (1.0f + rr));
            bt0[6] = (f16)1.0f;
        }
        a0 = 0.5f * t0v.x;
    }
    {
        float xx = t1v.y, yy = t1v.z, zz = t1v.w;
        float rr = sqrtf(fmaf(xx, xx, fmaf(yy, yy, zz * zz)));
        float irs = 1.0f / fmaxf(rr, 1e-8f);
        if (lane < 16) {
            bt1[1] = (f16)rr; bt1[2] = (f16)(xx * irs); bt1[3] = (f16)(yy * irs);
            bt1[4] = (f16)(zz * irs); bt1[5] = (f16)(1.0f / (1.0f + rr));
            bt1[6] = (f16)1.0f;
        }
        a1 = 0.5f * t1v.x;
    }
    {
        float xx = tov.y, yy = tov.z, zz = tov.w;
        float rr = sqrtf(fmaf(xx, xx, fmaf(yy, yy, zz * zz)));
        io = 1.0f / (1.0f + rr);
        ao = 0.5f * tov.x;
    }

    const f32x4 z4 = {0.f, 0.f, 0.f, 0.f};
    float icv = 0.0f, dsum = 0.0f;

    // prologue: stage ic slabs 0,1 into slots 0,1  (2 DMAs in flight invariant)
    stage16((const char*)(wsw + MLP_STRIDE) + tid * 16, lds + LDS_W + tid * 16);
    stage16((const char*)(wsw + MLP_STRIDE + SLAB_F16) + tid * 16,
            lds + LDS_W + 8192 + tid * 16);

    #pragma unroll 1
    for (int c = 0; c < 4; ++c) {
        const f16* wb     = wsw + (c == 0 ? MLP_STRIDE : 0);
        const float* bb   = bsc + (c == 0 ? 384 : 0);
        const float* Wout = (c == 0) ? ic_Wout : dp_Wout;
        const float* bout = (c == 0) ? ic_bout : dp_bout;
        const float tn = (c == 1) ? 0.22540333075851662f
                       : ((c == 2) ? 1.0f : 1.7745966692414834f);   // node+1

        f16x8 b0 = bt0, b1 = bt1;
        if (c != 0) { b0[0] = (f16)(a0 * tn); b1[0] = (f16)(a1 * tn); }

        f32x4 acc[4][2];

        #pragma unroll 1
        for (int sw = 0; sw < 13; ++sw) {
            // ---- pipelined sync: slab-sw DMA landed (1 still in flight) ----
            __asm__ __volatile__("" ::: "memory");
            __builtin_amdgcn_s_waitcnt(WAITCNT_VM1_LGKM0);
            __builtin_amdgcn_s_barrier();
            __asm__ __volatile__("" ::: "memory");

            // ---- ALWAYS stage slab sw+2 into slot (c+sw+2)&3 (uniform ledger;
            //      c==3 tail stages dp slab 0/1 into a dead slot, harmless) ----
            {
                int j = sw + 2;
                const char* gp = (j < 13) ? (const char*)(wb + j * SLAB_F16)
                                          : (const char*)(wsw + (j - 13) * SLAB_F16);
                stage16(gp + tid * 16,
                        lds + LDS_W + (((c + sw + 2) & 3) << 13) + tid * 16);
            }
            __asm__ __volatile__("" ::: "memory");

            const unsigned char* A = lds + LDS_W + (((c + sw) & 3) << 13);

            if (sw == 0) {
                // input layer: wave's 4 mt-tiles (K=32 in one MFMA)
                #pragma unroll
                for (int mtl = 0; mtl < 4; ++mtl) {
                    f16x8 a = *(const f16x8*)(A + (mtl << 10) + lane16);
                    acc[mtl][0] = mfma16(a, b0, z4);
                    acc[mtl][1] = mfma16(a, b1, z4);
                }
                #pragma unroll
                for (int mtl = 0; mtl < 4; ++mtl) {
                    int wa = K + (((mtb + mtl) << 5) ^ dh32);
                    #pragma unroll
                    for (int nt = 0; nt < 2; ++nt) {
                        f32x4 v = acc[mtl][nt];
                        uint2 o;
                        o.x = pk16(tanh_fast(v[0]), tanh_fast(v[1]));
                        o.y = pk16(tanh_fast(v[2]), tanh_fast(v[3]));
                        *(uint2*)(lds + wa + nt * 4096) = o;
                    }
                }
            } else {
                // hidden layer slab: l = (sw-1)/4, ks = (sw-1)%4
                int l  = (sw - 1) >> 2;
                int ks = (sw - 1) & 3;
                int ra = Kr + ((ks << 6) ^ dk64);
                f16x8 hb0 = *(const f16x8*)(lds + ra);
                f16x8 hb1 = *(const f16x8*)(lds + ra + 4096);
                if (ks == 0) {
                    const float* bl = bb + l * 128;
                    #pragma unroll
                    for (int mtl = 0; mtl < 4; ++mtl) {
                        f16x8 a = *(const f16x8*)(A + (mtl << 10) + lane16);
                        f32x4 b4 = *(const f32x4*)(bl + (mtb + mtl) * 16 + q * 4);
                        acc[mtl][0] = mfma16(a, hb0, b4);
                        acc[mtl][1] = mfma16(a, hb1, b4);
                    }
                } else {
                    #pragma unroll
                    for (int mtl = 0; mtl < 4; ++mtl) {
                        f16x8 a = *(const f16x8*)(A + (mtl << 10) + lane16);
                        acc[mtl][0] = mfma16(a, hb0, acc[mtl][0]);
                        acc[mtl][1] = mfma16(a, hb1, acc[mtl][1]);
                    }
                }
                if (ks == 3) {
                    // cross-wave RAW fix: all waves' layer-(l-1) H reads are
                    // consumed before anyone overwrites H with layer-l values.
                    __asm__ __volatile__("" ::: "memory");
                    __builtin_amdgcn_s_waitcnt(WAITCNT_LGKM0);
                    __builtin_amdgcn_s_barrier();
                    __asm__ __volatile__("" ::: "memory");
                    #pragma unroll
                    for (int mtl = 0; mtl < 4; ++mtl) {
                        int wa = K + (((mtb + mtl) << 5) ^ dh32);
                        #pragma unroll
                        for (int nt = 0; nt < 2; ++nt) {
                            f32x4 v = acc[mtl][nt];
                            uint2 o;
                            o.x = pk16(tanh_fast(v[0]), tanh_fast(v[1]));
                            o.y = pk16(tanh_fast(v[2]), tanh_fast(v[3]));
                            *(uint2*)(lds + wa + nt * 4096) = o;
                        }
                    }
                }
            }
        }

        // ---- output layer: 4 threads/sample (cross-wave H -> barrier) ----
        __asm__ __volatile__("" ::: "memory");
        __builtin_amdgcn_s_waitcnt(WAITCNT_VM0_LGKM0);
        __builtin_amdgcn_s_barrier();
        __asm__ __volatile__("" ::: "memory");
        {
            int s  = tid >> 2;
            int hq = tid & 3;
            const float* wp = Wout + hq * 32;
            float sum = 0.0f;
            #pragma unroll
            for (int u = 0; u < 4; ++u) {
                f16x8 hv = *(const f16x8*)(lds + h_addr(s, hq * 64 + u * 16));
                f32x4 w0 = *(const f32x4*)(wp + u * 8);
                f32x4 w1 = *(const f32x4*)(wp + u * 8 + 4);
                sum = fmaf((float)hv[0], w0[0], sum);
                sum = fmaf((float)hv[1], w0[1], sum);
                sum = fmaf((float)hv[2], w0[2], sum);
                sum = fmaf((float)hv[3], w0[3], sum);
                sum = fmaf((float)hv[4], w1[0], sum);
                sum = fmaf((float)hv[5], w1[1], sum);
                sum = fmaf((float)hv[6], w1[2], sum);
                sum = fmaf((float)hv[7], w1[3], sum);
            }
            sum += __shfl_xor(sum, 1, 64);
            sum += __shfl_xor(sum, 2, 64);
            float val = sum + bout[0];
            if (c == 0) icv = val;
            else        dsum = fmaf((c == 2) ? (8.0f / 9.0f) : (5.0f / 9.0f), val, dsum);
        }
    }

    if ((tid & 3) == 0) {
        out[p0 + (tid >> 2)] = (icv + ao * dsum) * io;
    }
}

extern "C" void kernel_launch(void* const* d_in, const int* in_sizes, int n_in,
                              void* d_out, int out_size, void* d_ws, size_t ws_size,
                              hipStream_t stream) {
    const float* tx      = (const float*)d_in[0];
    const float* dp_Win  = (const float*)d_in[1];
    const float* dp_bin  = (const float*)d_in[2];
    const float* dp_Wh   = (const float*)d_in[3];
    const float* dp_bh   = (const float*)d_in[4];
    const float* dp_Wout = (const float*)d_in[5];
    const float* dp_bout = (const float*)d_in[6];
    const float* ic_Win  = (const float*)d_in[7];
    const float* ic_bin  = (const float*)d_in[8];
    const float* ic_Wh   = (const float*)d_in[9];
    const float* ic_bh   = (const float*)d_in[10];
    const float* ic_Wout = (const float*)d_in[11];
    const float* ic_bout = (const float*)d_in[12];
    float* out = (float*)d_out;
    f16* wsw = (f16*)d_ws;

    int n = in_sizes[0] / 4;

    prep_kernel<<<dim3((2 * MLP_STRIDE + 768 + 255) / 256), dim3(256), 0, stream>>>(
        dp_Win, dp_bin, dp_Wh, dp_bh, ic_Win, ic_bin, ic_Wh, ic_bh, wsw);

    node_main<<<dim3(n / 128), dim3(NTHREADS), 0, stream>>>(
        tx, wsw, dp_Wout, dp_bout, ic_Wout, ic_bout, out);
}